// Round 1
// baseline (1620.966 us; speedup 1.0000x reference)
//
#include <hip/hip_runtime.h>

#define C 64

// MT[j*64+o] = sum_i linr_w[o][i] * lin_w[i][j]   (transposed combined matrix)
// bc[o]      = sum_i linr_w[o][i] * lin_b[i]
__global__ void precompute_wb(const float* __restrict__ lin_w,
                              const float* __restrict__ lin_b,
                              const float* __restrict__ linr_w,
                              float* __restrict__ MT,
                              float* __restrict__ bc) {
    int o = blockIdx.x;   // 64 blocks
    int j = threadIdx.x;  // 64 threads
    float acc = 0.f;
#pragma unroll
    for (int i = 0; i < C; ++i)
        acc += linr_w[o * C + i] * lin_w[i * C + j];
    MT[j * C + o] = acc;
    if (j == 0) {
        float b = 0.f;
#pragma unroll
        for (int i = 0; i < C; ++i) b += linr_w[o * C + i] * lin_b[i];
        bc[o] = b;
    }
}

// S[dst][:] += x[src][:]  (raw features, projection deferred); cnt[dst] += 1
// 16 lanes per edge, float4 per lane -> coalesced 256B row read per edge.
__global__ __launch_bounds__(256) void scatter_kernel(const float* __restrict__ x,
                                                      const int* __restrict__ ei,
                                                      float* S, float* cnt, int E) {
    int total = E * 16;
    int stride = gridDim.x * blockDim.x;
    for (int task = blockIdx.x * blockDim.x + threadIdx.x; task < total; task += stride) {
        int e = task >> 4;
        int c = task & 15;
        int src = ei[e];
        int dst = ei[E + e];
        const float4 v = *reinterpret_cast<const float4*>(x + (size_t)src * C + c * 4);
        float* p = S + (size_t)dst * C + c * 4;
        unsafeAtomicAdd(p + 0, v.x);
        unsafeAtomicAdd(p + 1, v.y);
        unsafeAtomicAdd(p + 2, v.z);
        unsafeAtomicAdd(p + 3, v.w);
        if (c == 0) unsafeAtomicAdd(cnt + dst, 1.0f);
    }
}

// out[n][o] = sum_j x[n][j]*linl_w[o][j] + linl_b[o]
//           + inv * sum_j S[n][j]*M[o][j] + [cnt>0]*bc[o]
// S may alias out (in-place): S rows staged to LDS before out rows are written.
__global__ __launch_bounds__(256) void output_kernel(const float* __restrict__ x,
                                                     const float* S,
                                                     const float* __restrict__ cnt,
                                                     const float* __restrict__ linl_w,
                                                     const float* __restrict__ linl_b,
                                                     const float* __restrict__ MT,
                                                     const float* __restrict__ bc,
                                                     float* out, int N) {
    __shared__ float wlT[C * C];  // wlT[j*64+o] = linl_w[o][j]
    __shared__ float mT[C * C];   // mT[j*64+o]
    __shared__ float xs[4 * C];
    __shared__ float ss[4 * C];
    int t = threadIdx.x;
    for (int idx = t; idx < C * C; idx += 256) {
        int j = idx >> 6, o = idx & 63;
        wlT[idx] = linl_w[o * C + j];
        mT[idx] = MT[idx];
    }
    __syncthreads();
    int nl = t >> 6;   // node within tile (constant per wave)
    int o = t & 63;    // output channel = lane
    int ntiles = (N + 3) >> 2;
    for (int tile = blockIdx.x; tile < ntiles; tile += gridDim.x) {
        int n0 = tile * 4;
        int gi = n0 * C + t;
        if (gi < N * C) {
            xs[t] = x[gi];
            ss[t] = S[gi];
        }
        __syncthreads();
        int n = n0 + nl;
        if (n < N) {
            float cn = cnt[n];
            float inv = 1.0f / fmaxf(cn, 1.0f);
            float ind = cn > 0.f ? 1.f : 0.f;
            float a1 = 0.f, a2 = 0.f;
#pragma unroll
            for (int j = 0; j < C; ++j) {
                a1 = fmaf(xs[nl * C + j], wlT[j * C + o], a1);
                a2 = fmaf(ss[nl * C + j], mT[j * C + o], a2);
            }
            out[n * C + o] = a1 + linl_b[o] + inv * a2 + ind * bc[o];
        }
        __syncthreads();
    }
}

extern "C" void kernel_launch(void* const* d_in, const int* in_sizes, int n_in,
                              void* d_out, int out_size, void* d_ws, size_t ws_size,
                              hipStream_t stream) {
    const float* x      = (const float*)d_in[0];
    const int*   ei     = (const int*)d_in[1];
    const float* lin_w  = (const float*)d_in[2];
    const float* lin_b  = (const float*)d_in[3];
    const float* linl_w = (const float*)d_in[4];
    const float* linl_b = (const float*)d_in[5];
    const float* linr_w = (const float*)d_in[6];

    int N = in_sizes[0] / C;
    int E = in_sizes[1] / 2;

    float* S   = (float*)d_out;          // accumulate aggregation in d_out (N*64 f32)
    float* cnt = (float*)d_ws;           // N f32
    float* MT  = cnt + N;                // 4096 f32
    float* bc  = MT + C * C;             // 64 f32

    // zero accumulators
    hipMemsetAsync(d_out, 0, (size_t)N * C * sizeof(float), stream);
    hipMemsetAsync(cnt, 0, (size_t)N * sizeof(float), stream);

    precompute_wb<<<C, C, 0, stream>>>(lin_w, lin_b, linr_w, MT, bc);

    int tasks = E * 16;
    int sblocks = (tasks + 255) / 256;
    if (sblocks > 2048) sblocks = 2048;
    scatter_kernel<<<sblocks, 256, 0, stream>>>(x, ei, S, cnt, E);

    output_kernel<<<1024, 256, 0, stream>>>(x, S, cnt, linl_w, linl_b, MT, bc,
                                            (float*)d_out, N);
}

// Round 4
// 565.880 us; speedup vs baseline: 2.8645x; 2.8645x over previous
//
#include <hip/hip_runtime.h>

#define C 64

// MT[j*64+o] = sum_i linr_w[o][i] * lin_w[i][j]; bc[o] = linr_w[o]·lin_b
__global__ void precompute_wb(const float* __restrict__ lin_w,
                              const float* __restrict__ lin_b,
                              const float* __restrict__ linr_w,
                              float* __restrict__ MT,
                              float* __restrict__ bc) {
    int o = blockIdx.x;
    int j = threadIdx.x;
    float acc = 0.f;
#pragma unroll
    for (int i = 0; i < C; ++i)
        acc += linr_w[o * C + i] * lin_w[i * C + j];
    MT[j * C + o] = acc;
    if (j == 0) {
        float b = 0.f;
#pragma unroll
        for (int i = 0; i < C; ++i) b += linr_w[o * C + i] * lin_b[i];
        bc[o] = b;
    }
}

// degree histogram: cnt[dst]++
__global__ __launch_bounds__(256) void hist_kernel(const int* __restrict__ ei,
                                                   int* cnt, int E) {
    int stride = gridDim.x * blockDim.x;
    for (int e = blockIdx.x * blockDim.x + threadIdx.x; e < E; e += stride)
        atomicAdd(&cnt[ei[E + e]], 1);
}

// scan pass 1: per-block (1024 elems) exclusive scan + block sums
__global__ __launch_bounds__(256) void scan1(const int* __restrict__ cnt,
                                             int* offs, int* bsums, int N) {
    __shared__ int tmp[256];
    int b = blockIdx.x, t = threadIdx.x;
    int base = b * 1024 + t * 4;
    int c0 = base + 0 < N ? cnt[base + 0] : 0;
    int c1 = base + 1 < N ? cnt[base + 1] : 0;
    int c2 = base + 2 < N ? cnt[base + 2] : 0;
    int c3 = base + 3 < N ? cnt[base + 3] : 0;
    int s = c0 + c1 + c2 + c3;
    tmp[t] = s;
    __syncthreads();
    for (int off = 1; off < 256; off <<= 1) {
        int u = (t >= off) ? tmp[t - off] : 0;
        __syncthreads();
        tmp[t] += u;
        __syncthreads();
    }
    int excl = tmp[t] - s;
    if (base + 0 < N) offs[base + 0] = excl; excl += c0;
    if (base + 1 < N) offs[base + 1] = excl; excl += c1;
    if (base + 2 < N) offs[base + 2] = excl; excl += c2;
    if (base + 3 < N) offs[base + 3] = excl;
    if (t == 255) bsums[b] = tmp[255];
}

// scan pass 2: exclusive scan of block sums (nb <= 256), single block
__global__ __launch_bounds__(256) void scan2(int* bsums, int nb) {
    __shared__ int tmp[256];
    int t = threadIdx.x;
    int v = t < nb ? bsums[t] : 0;
    tmp[t] = v;
    __syncthreads();
    for (int off = 1; off < 256; off <<= 1) {
        int u = (t >= off) ? tmp[t - off] : 0;
        __syncthreads();
        tmp[t] += u;
        __syncthreads();
    }
    if (t < nb) bsums[t] = tmp[t] - v;
}

// scan pass 3: add block offsets; init write cursors
__global__ __launch_bounds__(256) void scan3(int* offs, const int* __restrict__ bsums,
                                             int* cursor, int N) {
    int stride = gridDim.x * blockDim.x;
    for (int i = blockIdx.x * blockDim.x + threadIdx.x; i < N; i += stride) {
        int v = offs[i] + bsums[i >> 10];
        offs[i] = v;
        cursor[i] = v;
    }
}

// bucket-scatter src ids grouped by dst
__global__ __launch_bounds__(256) void scatter_ids(const int* __restrict__ ei,
                                                   int* cursor, int* ss, int E) {
    int stride = gridDim.x * blockDim.x;
    for (int e = blockIdx.x * blockDim.x + threadIdx.x; e < E; e += stride) {
        int dst = ei[E + e];
        int p = atomicAdd(&cursor[dst], 1);
        ss[p] = ei[e];
    }
}

// per node (one wave each): agg = sum_{s in bucket} x[s][:]; then
// out[n][o] = x[n]·linl_w[o] + linl_b[o] + (agg/max(d,1))·M[o] + [d>0]*bc[o]
__global__ __launch_bounds__(256) void fused_kernel(const float* __restrict__ x,
                                                    const int* __restrict__ ss,
                                                    const int* __restrict__ offs,
                                                    const int* __restrict__ cnt,
                                                    const float* __restrict__ linl_w,
                                                    const float* __restrict__ linl_b,
                                                    const float* __restrict__ MT,
                                                    const float* __restrict__ bc,
                                                    float* __restrict__ out, int N) {
    __shared__ float wlT[C * C];  // wlT[j*64+o] = linl_w[o][j]
    __shared__ float mT[C * C];
    __shared__ float xs[4][C];
    __shared__ float as[4][C];
    int t = threadIdx.x;
    for (int idx = t; idx < C * C; idx += 256) {
        int j = idx >> 6, o = idx & 63;
        wlT[idx] = linl_w[o * C + j];
        mT[idx] = MT[idx];
    }
    __syncthreads();
    int w = t >> 6, lane = t & 63;
    for (int n = blockIdx.x * 4 + w; n < N; n += gridDim.x * 4) {
        int start = offs[n];
        int deg = cnt[n];
        float acc = 0.f;
        for (int i = 0; i < deg; ++i) {
            int s = ss[start + i];
            acc += x[(size_t)s * C + lane];
        }
        as[w][lane] = acc;
        xs[w][lane] = x[(size_t)n * C + lane];
        __builtin_amdgcn_wave_barrier();  // intra-wave LDS RAW ordering hint
        float inv = 1.0f / (float)max(deg, 1);
        float ind = deg > 0 ? 1.f : 0.f;
        float a1 = 0.f, a2 = 0.f;
#pragma unroll
        for (int j = 0; j < C; ++j) {
            a1 = fmaf(xs[w][j], wlT[j * C + lane], a1);
            a2 = fmaf(as[w][j], mT[j * C + lane], a2);
        }
        out[(size_t)n * C + lane] = a1 + linl_b[lane] + inv * a2 + ind * bc[lane];
        __builtin_amdgcn_wave_barrier();
    }
}

extern "C" void kernel_launch(void* const* d_in, const int* in_sizes, int n_in,
                              void* d_out, int out_size, void* d_ws, size_t ws_size,
                              hipStream_t stream) {
    const float* x      = (const float*)d_in[0];
    const int*   ei     = (const int*)d_in[1];
    const float* lin_w  = (const float*)d_in[2];
    const float* lin_b  = (const float*)d_in[3];
    const float* linl_w = (const float*)d_in[4];
    const float* linl_b = (const float*)d_in[5];
    const float* linr_w = (const float*)d_in[6];

    int N = in_sizes[0] / C;
    int E = in_sizes[1] / 2;

    // ws layout (4B units): cnt[N] | offs[N] | cursor[N] | bsums[256] | MT[4096] | bc[64] | ss[E]
    int* cnt    = (int*)d_ws;
    int* offs   = cnt + N;
    int* cursor = offs + N;
    int* bsums  = cursor + N;
    float* MT   = (float*)(bsums + 256);
    float* bc   = MT + C * C;
    int* ss     = (int*)(bc + C);

    hipMemsetAsync(cnt, 0, (size_t)N * sizeof(int), stream);

    precompute_wb<<<C, C, 0, stream>>>(lin_w, lin_b, linr_w, MT, bc);

    hist_kernel<<<2048, 256, 0, stream>>>(ei, cnt, E);

    int nb1 = (N + 1023) / 1024;
    scan1<<<nb1, 256, 0, stream>>>(cnt, offs, bsums, N);
    scan2<<<1, 256, 0, stream>>>(bsums, nb1);
    scan3<<<2048, 256, 0, stream>>>(offs, bsums, cursor, N);

    scatter_ids<<<2048, 256, 0, stream>>>(ei, cursor, ss, E);

    fused_kernel<<<2048, 256, 0, stream>>>(x, ss, offs, cnt, linl_w, linl_b, MT, bc,
                                           (float*)d_out, N);
}

// Round 5
// 414.749 us; speedup vs baseline: 3.9083x; 1.3644x over previous
//
#include <hip/hip_runtime.h>

#define C 64

__device__ __forceinline__ float lanebc(float v, int l) {
    return __uint_as_float(__builtin_amdgcn_readlane(__float_as_uint(v), l));
}

// Mrow[o*64+j] = sum_i linr_w[o][i] * lin_w[i][j]; bc[o] = linr_w[o]·lin_b
__global__ void precompute_wb(const float* __restrict__ lin_w,
                              const float* __restrict__ lin_b,
                              const float* __restrict__ linr_w,
                              float* __restrict__ Mrow,
                              float* __restrict__ bc) {
    int o = blockIdx.x;
    int j = threadIdx.x;
    float acc = 0.f;
#pragma unroll
    for (int i = 0; i < C; ++i)
        acc += linr_w[o * C + i] * lin_w[i * C + j];
    Mrow[o * C + j] = acc;
    if (j == 0) {
        float b = 0.f;
#pragma unroll
        for (int i = 0; i < C; ++i) b += linr_w[o * C + i] * lin_b[i];
        bc[o] = b;
    }
}

// degree histogram: cnt[dst]++  (int4-vectorized when E%4==0)
__global__ __launch_bounds__(256) void hist_kernel(const int* __restrict__ ei,
                                                   int* cnt, int E) {
    int i = blockIdx.x * blockDim.x + threadIdx.x;
    int stride = gridDim.x * blockDim.x;
    if ((E & 3) == 0) {
        const int4* d4 = (const int4*)(ei + E);
        int n4 = E >> 2;
        for (int k = i; k < n4; k += stride) {
            int4 v = d4[k];
            atomicAdd(&cnt[v.x], 1);
            atomicAdd(&cnt[v.y], 1);
            atomicAdd(&cnt[v.z], 1);
            atomicAdd(&cnt[v.w], 1);
        }
    } else {
        for (int e = i; e < E; e += stride) atomicAdd(&cnt[ei[E + e]], 1);
    }
}

// scan pass 1: per-block (1024 elems) exclusive scan + block sums
__global__ __launch_bounds__(256) void scan1(const int* __restrict__ cnt,
                                             int* offs, int* bsums, int N) {
    __shared__ int tmp[256];
    int b = blockIdx.x, t = threadIdx.x;
    int base = b * 1024 + t * 4;
    int c0 = base + 0 < N ? cnt[base + 0] : 0;
    int c1 = base + 1 < N ? cnt[base + 1] : 0;
    int c2 = base + 2 < N ? cnt[base + 2] : 0;
    int c3 = base + 3 < N ? cnt[base + 3] : 0;
    int s = c0 + c1 + c2 + c3;
    tmp[t] = s;
    __syncthreads();
    for (int off = 1; off < 256; off <<= 1) {
        int u = (t >= off) ? tmp[t - off] : 0;
        __syncthreads();
        tmp[t] += u;
        __syncthreads();
    }
    int excl = tmp[t] - s;
    if (base + 0 < N) offs[base + 0] = excl; excl += c0;
    if (base + 1 < N) offs[base + 1] = excl; excl += c1;
    if (base + 2 < N) offs[base + 2] = excl; excl += c2;
    if (base + 3 < N) offs[base + 3] = excl;
    if (t == 255) bsums[b] = tmp[255];
}

// scan pass 2: exclusive scan of block sums (nb <= 256), single block
__global__ __launch_bounds__(256) void scan2(int* bsums, int nb) {
    __shared__ int tmp[256];
    int t = threadIdx.x;
    int v = t < nb ? bsums[t] : 0;
    tmp[t] = v;
    __syncthreads();
    for (int off = 1; off < 256; off <<= 1) {
        int u = (t >= off) ? tmp[t - off] : 0;
        __syncthreads();
        tmp[t] += u;
        __syncthreads();
    }
    if (t < nb) bsums[t] = tmp[t] - v;
}

// scan pass 3: add block offsets; init write cursors
__global__ __launch_bounds__(256) void scan3(int* offs, const int* __restrict__ bsums,
                                             int* cursor, int N) {
    int stride = gridDim.x * blockDim.x;
    for (int i = blockIdx.x * blockDim.x + threadIdx.x; i < N; i += stride) {
        int v = offs[i] + bsums[i >> 10];
        offs[i] = v;
        cursor[i] = v;
    }
}

// bucket-scatter src ids grouped by dst (int4-vectorized)
__global__ __launch_bounds__(256) void scatter_ids(const int* __restrict__ ei,
                                                   int* cursor, int* ss, int E) {
    int i = blockIdx.x * blockDim.x + threadIdx.x;
    int stride = gridDim.x * blockDim.x;
    if ((E & 3) == 0) {
        const int4* s4 = (const int4*)ei;
        const int4* d4 = (const int4*)(ei + E);
        int n4 = E >> 2;
        for (int k = i; k < n4; k += stride) {
            int4 sv = s4[k];
            int4 dv = d4[k];
            ss[atomicAdd(&cursor[dv.x], 1)] = sv.x;
            ss[atomicAdd(&cursor[dv.y], 1)] = sv.y;
            ss[atomicAdd(&cursor[dv.z], 1)] = sv.z;
            ss[atomicAdd(&cursor[dv.w], 1)] = sv.w;
        }
    } else {
        for (int e = i; e < E; e += stride) {
            int dst = ei[E + e];
            int p = atomicAdd(&cursor[dst], 1);
            ss[p] = ei[e];
        }
    }
}

// gather: agg[n][:] = sum over bucket of x[s][:]
// 4 groups of 16 lanes; each group loads one edge row as float4/lane; quad-unrolled MLP.
__global__ __launch_bounds__(256) void gather_kernel(const float* __restrict__ x,
                                                     const int* __restrict__ ss,
                                                     const int* __restrict__ offs,
                                                     const int* __restrict__ cnt,
                                                     float* __restrict__ agg, int N) {
    int t = threadIdx.x;
    int w = t >> 6, lane = t & 63;
    int lg = lane >> 4, li = lane & 15;
    for (int n = blockIdx.x * 4 + w; n < N; n += gridDim.x * 4) {
        int start = offs[n];
        int deg = cnt[n];
        float a0[4] = {0, 0, 0, 0}, a1[4] = {0, 0, 0, 0};
        float a2[4] = {0, 0, 0, 0}, a3[4] = {0, 0, 0, 0};
        for (int base = 0; base < deg; base += 64) {
            int cdeg = min(deg - base, 64);
            int sid = ss[start + base + min(lane, cdeg - 1)];
            int nsteps = (cdeg + 3) >> 2;
            int tt = 0;
            for (; tt + 4 <= nsteps; tt += 4) {
                int i0 = tt * 4 + lg;
                int i3 = i0 + 12;
                int s0 = __shfl(sid, i0);
                int s1 = __shfl(sid, i0 + 4);
                int s2 = __shfl(sid, i0 + 8);
                int s3 = __shfl(sid, min(i3, cdeg - 1));
                float w3 = (i3 < cdeg) ? 1.f : 0.f;
                float4 v0 = *(const float4*)(x + (size_t)s0 * C + (li << 2));
                float4 v1 = *(const float4*)(x + (size_t)s1 * C + (li << 2));
                float4 v2 = *(const float4*)(x + (size_t)s2 * C + (li << 2));
                float4 v3 = *(const float4*)(x + (size_t)s3 * C + (li << 2));
                a0[0] += v0.x; a0[1] += v0.y; a0[2] += v0.z; a0[3] += v0.w;
                a1[0] += v1.x; a1[1] += v1.y; a1[2] += v1.z; a1[3] += v1.w;
                a2[0] += v2.x; a2[1] += v2.y; a2[2] += v2.z; a2[3] += v2.w;
                a3[0] = fmaf(w3, v3.x, a3[0]); a3[1] = fmaf(w3, v3.y, a3[1]);
                a3[2] = fmaf(w3, v3.z, a3[2]); a3[3] = fmaf(w3, v3.w, a3[3]);
            }
            for (; tt + 2 <= nsteps; tt += 2) {
                int i0 = tt * 4 + lg;
                int i1 = i0 + 4;
                int s0 = __shfl(sid, i0);
                int s1 = __shfl(sid, min(i1, cdeg - 1));
                float w1 = (i1 < cdeg) ? 1.f : 0.f;
                float4 v0 = *(const float4*)(x + (size_t)s0 * C + (li << 2));
                float4 v1 = *(const float4*)(x + (size_t)s1 * C + (li << 2));
                a0[0] += v0.x; a0[1] += v0.y; a0[2] += v0.z; a0[3] += v0.w;
                a1[0] = fmaf(w1, v1.x, a1[0]); a1[1] = fmaf(w1, v1.y, a1[1]);
                a1[2] = fmaf(w1, v1.z, a1[2]); a1[3] = fmaf(w1, v1.w, a1[3]);
            }
            for (; tt < nsteps; ++tt) {
                int i0 = tt * 4 + lg;
                int s0 = __shfl(sid, min(i0, cdeg - 1));
                float w0 = (i0 < cdeg) ? 1.f : 0.f;
                float4 v0 = *(const float4*)(x + (size_t)s0 * C + (li << 2));
                a0[0] = fmaf(w0, v0.x, a0[0]); a0[1] = fmaf(w0, v0.y, a0[1]);
                a0[2] = fmaf(w0, v0.z, a0[2]); a0[3] = fmaf(w0, v0.w, a0[3]);
            }
        }
#pragma unroll
        for (int k = 0; k < 4; ++k) a0[k] += a1[k] + a2[k] + a3[k];
#pragma unroll
        for (int k = 0; k < 4; ++k) {
            a0[k] += __shfl_xor(a0[k], 16);
            a0[k] += __shfl_xor(a0[k], 32);
        }
        if (lane < 16) {
            float4 r;
            r.x = a0[0]; r.y = a0[1]; r.z = a0[2]; r.w = a0[3];
            *(float4*)(agg + (size_t)n * C + (li << 2)) = r;
        }
    }
}

// out[n][o] = x[n]·wl[o] + bl[o] + inv * agg[n]·mm[o] + ind*bc[o]
// Weights live in registers (lane = output channel o); operand broadcast via v_readlane.
// agg aliases out: each row is fully loaded to registers before being overwritten,
// and rows are wave-disjoint, so in-place is safe.
__global__ __launch_bounds__(256, 2) void matmul_kernel(const float* __restrict__ x,
                                                        const float* agg,
                                                        const int* __restrict__ cnt,
                                                        const float* __restrict__ linl_w,
                                                        const float* __restrict__ linl_b,
                                                        const float* __restrict__ Mrow,
                                                        const float* __restrict__ bc,
                                                        float* out, int N) {
    int t = threadIdx.x;
    int w = t >> 6, lane = t & 63;
    float wl[C], mm[C];
#pragma unroll
    for (int j = 0; j < C; j += 4) {
        float4 a = *(const float4*)(linl_w + (size_t)lane * C + j);
        wl[j] = a.x; wl[j + 1] = a.y; wl[j + 2] = a.z; wl[j + 3] = a.w;
        float4 b = *(const float4*)(Mrow + (size_t)lane * C + j);
        mm[j] = b.x; mm[j + 1] = b.y; mm[j + 2] = b.z; mm[j + 3] = b.w;
    }
    float bl = linl_b[lane];
    float bcv = bc[lane];
    for (int n = blockIdx.x * 4 + w; n < N; n += gridDim.x * 4) {
        float xval = x[(size_t)n * C + lane];
        float aval = agg[(size_t)n * C + lane];
        int deg = cnt[n];
        float inv = 1.0f / (float)max(deg, 1);
        float ind = deg > 0 ? 1.f : 0.f;
        float acc1 = bl, acc2 = 0.f;
#pragma unroll
        for (int j = 0; j < C; ++j) {
            acc1 = fmaf(lanebc(xval, j), wl[j], acc1);
            acc2 = fmaf(lanebc(aval, j), mm[j], acc2);
        }
        out[(size_t)n * C + lane] = acc1 + inv * acc2 + ind * bcv;
    }
}

extern "C" void kernel_launch(void* const* d_in, const int* in_sizes, int n_in,
                              void* d_out, int out_size, void* d_ws, size_t ws_size,
                              hipStream_t stream) {
    const float* x      = (const float*)d_in[0];
    const int*   ei     = (const int*)d_in[1];
    const float* lin_w  = (const float*)d_in[2];
    const float* lin_b  = (const float*)d_in[3];
    const float* linl_w = (const float*)d_in[4];
    const float* linl_b = (const float*)d_in[5];
    const float* linr_w = (const float*)d_in[6];

    int N = in_sizes[0] / C;
    int E = in_sizes[1] / 2;

    // ws layout (4B units): cnt[N] | offs[N] | cursor[N] | bsums[256] | Mrow[4096] | bc[64] | ss[E]
    int* cnt    = (int*)d_ws;
    int* offs   = cnt + N;
    int* cursor = offs + N;
    int* bsums  = cursor + N;
    float* Mrow = (float*)(bsums + 256);
    float* bc   = Mrow + C * C;
    int* ss     = (int*)(bc + C);

    float* agg = (float*)d_out;  // raw neighbor sums accumulate in d_out

    hipMemsetAsync(cnt, 0, (size_t)N * sizeof(int), stream);

    precompute_wb<<<C, C, 0, stream>>>(lin_w, lin_b, linr_w, Mrow, bc);

    hist_kernel<<<2048, 256, 0, stream>>>(ei, cnt, E);

    int nb1 = (N + 1023) / 1024;
    scan1<<<nb1, 256, 0, stream>>>(cnt, offs, bsums, N);
    scan2<<<1, 256, 0, stream>>>(bsums, nb1);
    scan3<<<2048, 256, 0, stream>>>(offs, bsums, cursor, N);

    scatter_ids<<<2048, 256, 0, stream>>>(ei, cursor, ss, E);

    gather_kernel<<<2048, 256, 0, stream>>>(x, ss, offs, cnt, agg, N);

    matmul_kernel<<<2048, 256, 0, stream>>>(x, agg, cnt, linl_w, linl_b, Mrow, bc,
                                            (float*)d_out, N);
}

// Round 7
// 366.587 us; speedup vs baseline: 4.4218x; 1.1314x over previous
//
#include <hip/hip_runtime.h>

#define C 64
#define NPART 8

__device__ __forceinline__ float lanebc(float v, int l) {
    return __uint_as_float(__builtin_amdgcn_readlane(__float_as_uint(v), l));
}

// Mrow[o*64+j] = sum_i linr_w[o][i] * lin_w[i][j]; bc[o] = linr_w[o]·lin_b
__global__ void precompute_wb(const float* __restrict__ lin_w,
                              const float* __restrict__ lin_b,
                              const float* __restrict__ linr_w,
                              float* __restrict__ Mrow,
                              float* __restrict__ bc) {
    int o = blockIdx.x;
    int j = threadIdx.x;
    float acc = 0.f;
#pragma unroll
    for (int i = 0; i < C; ++i)
        acc += linr_w[o * C + i] * lin_w[i * C + j];
    Mrow[o * C + j] = acc;
    if (j == 0) {
        float b = 0.f;
#pragma unroll
        for (int i = 0; i < C; ++i) b += linr_w[o * C + i] * lin_b[i];
        bc[o] = b;
    }
}

// degree histogram, XCD-partitioned by dst range: block handles partition (b&7);
// scans whole dst array, counts only its range -> cnt lines owned by one XCD L2.
__global__ __launch_bounds__(256) void hist_kernel(const int* __restrict__ ei,
                                                   int* cnt, int E, int N) {
    int part = blockIdx.x & (NPART - 1);
    int R = (N + NPART - 1) / NPART;
    int lo = part * R;
    int hi = min(N, lo + R);
    int bid = blockIdx.x >> 3;
    int nblk = gridDim.x >> 3;
    int i = bid * blockDim.x + threadIdx.x;
    int stride = nblk * blockDim.x;
    if ((E & 3) == 0) {
        const int4* d4 = (const int4*)(ei + E);
        int n4 = E >> 2;
        for (int k = i; k < n4; k += stride) {
            int4 v = d4[k];
            if (v.x >= lo && v.x < hi) atomicAdd(&cnt[v.x], 1);
            if (v.y >= lo && v.y < hi) atomicAdd(&cnt[v.y], 1);
            if (v.z >= lo && v.z < hi) atomicAdd(&cnt[v.z], 1);
            if (v.w >= lo && v.w < hi) atomicAdd(&cnt[v.w], 1);
        }
    } else {
        for (int e = i; e < E; e += stride) {
            int d = ei[E + e];
            if (d >= lo && d < hi) atomicAdd(&cnt[d], 1);
        }
    }
}

// scan pass 1: per-block (1024 elems) exclusive scan + block sums
__global__ __launch_bounds__(256) void scan1(const int* __restrict__ cnt,
                                             int* offs, int* bsums, int N) {
    __shared__ int tmp[256];
    int b = blockIdx.x, t = threadIdx.x;
    int base = b * 1024 + t * 4;
    int c0 = base + 0 < N ? cnt[base + 0] : 0;
    int c1 = base + 1 < N ? cnt[base + 1] : 0;
    int c2 = base + 2 < N ? cnt[base + 2] : 0;
    int c3 = base + 3 < N ? cnt[base + 3] : 0;
    int s = c0 + c1 + c2 + c3;
    tmp[t] = s;
    __syncthreads();
    for (int off = 1; off < 256; off <<= 1) {
        int u = (t >= off) ? tmp[t - off] : 0;
        __syncthreads();
        tmp[t] += u;
        __syncthreads();
    }
    int excl = tmp[t] - s;
    if (base + 0 < N) offs[base + 0] = excl; excl += c0;
    if (base + 1 < N) offs[base + 1] = excl; excl += c1;
    if (base + 2 < N) offs[base + 2] = excl; excl += c2;
    if (base + 3 < N) offs[base + 3] = excl;
    if (t == 255) bsums[b] = tmp[255];
}

// scan pass 2: exclusive scan of block sums (nb <= 256), single block
__global__ __launch_bounds__(256) void scan2(int* bsums, int nb) {
    __shared__ int tmp[256];
    int t = threadIdx.x;
    int v = t < nb ? bsums[t] : 0;
    tmp[t] = v;
    __syncthreads();
    for (int off = 1; off < 256; off <<= 1) {
        int u = (t >= off) ? tmp[t - off] : 0;
        __syncthreads();
        tmp[t] += u;
        __syncthreads();
    }
    if (t < nb) bsums[t] = tmp[t] - v;
}

// scan pass 3: add block offsets; init write cursors
__global__ __launch_bounds__(256) void scan3(int* offs, const int* __restrict__ bsums,
                                             int* cursor, int N) {
    int stride = gridDim.x * blockDim.x;
    for (int i = blockIdx.x * blockDim.x + threadIdx.x; i < N; i += stride) {
        int v = offs[i] + bsums[i >> 10];
        offs[i] = v;
        cursor[i] = v;
    }
}

// bucket-scatter src ids grouped by dst, XCD-partitioned by dst range:
// each partition's ss segment + cursor range is written by blocks on one XCD only,
// so partial 64B lines coalesce in that L2 and write back once (kills the 17x
// write amplification seen as WRITE_SIZE=108MB for a 6.4MB buffer).
__global__ __launch_bounds__(256) void scatter_ids(const int* __restrict__ ei,
                                                   int* cursor, int* ss, int E, int N) {
    int part = blockIdx.x & (NPART - 1);
    int R = (N + NPART - 1) / NPART;
    int lo = part * R;
    int hi = min(N, lo + R);
    int bid = blockIdx.x >> 3;
    int nblk = gridDim.x >> 3;
    int i = bid * blockDim.x + threadIdx.x;
    int stride = nblk * blockDim.x;
    if ((E & 3) == 0) {
        const int4* s4 = (const int4*)ei;
        const int4* d4 = (const int4*)(ei + E);
        int n4 = E >> 2;
        for (int k = i; k < n4; k += stride) {
            int4 dv = d4[k];
            int4 sv = s4[k];
            if (dv.x >= lo && dv.x < hi) ss[atomicAdd(&cursor[dv.x], 1)] = sv.x;
            if (dv.y >= lo && dv.y < hi) ss[atomicAdd(&cursor[dv.y], 1)] = sv.y;
            if (dv.z >= lo && dv.z < hi) ss[atomicAdd(&cursor[dv.z], 1)] = sv.z;
            if (dv.w >= lo && dv.w < hi) ss[atomicAdd(&cursor[dv.w], 1)] = sv.w;
        }
    } else {
        for (int e = i; e < E; e += stride) {
            int d = ei[E + e];
            if (d >= lo && d < hi) ss[atomicAdd(&cursor[d], 1)] = ei[e];
        }
    }
}

// gather: agg[n][:] = sum over bucket of x[s][:]
// 4 groups of 16 lanes; each group loads one edge row as float4/lane; quad-unrolled MLP.
__global__ __launch_bounds__(256) void gather_kernel(const float* __restrict__ x,
                                                     const int* __restrict__ ss,
                                                     const int* __restrict__ offs,
                                                     const int* __restrict__ cnt,
                                                     float* __restrict__ agg, int N) {
    int t = threadIdx.x;
    int w = t >> 6, lane = t & 63;
    int lg = lane >> 4, li = lane & 15;
    for (int n = blockIdx.x * 4 + w; n < N; n += gridDim.x * 4) {
        int start = offs[n];
        int deg = cnt[n];
        float a0[4] = {0, 0, 0, 0}, a1[4] = {0, 0, 0, 0};
        float a2[4] = {0, 0, 0, 0}, a3[4] = {0, 0, 0, 0};
        for (int base = 0; base < deg; base += 64) {
            int cdeg = min(deg - base, 64);
            int sid = ss[start + base + min(lane, cdeg - 1)];
            int nsteps = (cdeg + 3) >> 2;
            int tt = 0;
            for (; tt + 4 <= nsteps; tt += 4) {
                int i0 = tt * 4 + lg;
                int i3 = i0 + 12;
                int s0 = __shfl(sid, i0);
                int s1 = __shfl(sid, i0 + 4);
                int s2 = __shfl(sid, i0 + 8);
                int s3 = __shfl(sid, min(i3, cdeg - 1));
                float w3 = (i3 < cdeg) ? 1.f : 0.f;
                float4 v0 = *(const float4*)(x + (size_t)s0 * C + (li << 2));
                float4 v1 = *(const float4*)(x + (size_t)s1 * C + (li << 2));
                float4 v2 = *(const float4*)(x + (size_t)s2 * C + (li << 2));
                float4 v3 = *(const float4*)(x + (size_t)s3 * C + (li << 2));
                a0[0] += v0.x; a0[1] += v0.y; a0[2] += v0.z; a0[3] += v0.w;
                a1[0] += v1.x; a1[1] += v1.y; a1[2] += v1.z; a1[3] += v1.w;
                a2[0] += v2.x; a2[1] += v2.y; a2[2] += v2.z; a2[3] += v2.w;
                a3[0] = fmaf(w3, v3.x, a3[0]); a3[1] = fmaf(w3, v3.y, a3[1]);
                a3[2] = fmaf(w3, v3.z, a3[2]); a3[3] = fmaf(w3, v3.w, a3[3]);
            }
            for (; tt + 2 <= nsteps; tt += 2) {
                int i0 = tt * 4 + lg;
                int i1 = i0 + 4;
                int s0 = __shfl(sid, i0);
                int s1 = __shfl(sid, min(i1, cdeg - 1));
                float w1 = (i1 < cdeg) ? 1.f : 0.f;
                float4 v0 = *(const float4*)(x + (size_t)s0 * C + (li << 2));
                float4 v1 = *(const float4*)(x + (size_t)s1 * C + (li << 2));
                a0[0] += v0.x; a0[1] += v0.y; a0[2] += v0.z; a0[3] += v0.w;
                a1[0] = fmaf(w1, v1.x, a1[0]); a1[1] = fmaf(w1, v1.y, a1[1]);
                a1[2] = fmaf(w1, v1.z, a1[2]); a1[3] = fmaf(w1, v1.w, a1[3]);
            }
            for (; tt < nsteps; ++tt) {
                int i0 = tt * 4 + lg;
                int s0 = __shfl(sid, min(i0, cdeg - 1));
                float w0 = (i0 < cdeg) ? 1.f : 0.f;
                float4 v0 = *(const float4*)(x + (size_t)s0 * C + (li << 2));
                a0[0] = fmaf(w0, v0.x, a0[0]); a0[1] = fmaf(w0, v0.y, a0[1]);
                a0[2] = fmaf(w0, v0.z, a0[2]); a0[3] = fmaf(w0, v0.w, a0[3]);
            }
        }
#pragma unroll
        for (int k = 0; k < 4; ++k) a0[k] += a1[k] + a2[k] + a3[k];
#pragma unroll
        for (int k = 0; k < 4; ++k) {
            a0[k] += __shfl_xor(a0[k], 16);
            a0[k] += __shfl_xor(a0[k], 32);
        }
        if (lane < 16) {
            float4 r;
            r.x = a0[0]; r.y = a0[1]; r.z = a0[2]; r.w = a0[3];
            *(float4*)(agg + (size_t)n * C + (li << 2)) = r;
        }
    }
}

// out[n][o] = x[n]·wl[o] + bl[o] + inv * agg[n]·mm[o] + ind*bc[o]
// Weights live in registers (lane = output channel o); operand broadcast via v_readlane.
// agg aliases out: each row is fully loaded to registers before being overwritten,
// and rows are wave-disjoint, so in-place is safe.
__global__ __launch_bounds__(256, 2) void matmul_kernel(const float* __restrict__ x,
                                                        const float* agg,
                                                        const int* __restrict__ cnt,
                                                        const float* __restrict__ linl_w,
                                                        const float* __restrict__ linl_b,
                                                        const float* __restrict__ Mrow,
                                                        const float* __restrict__ bc,
                                                        float* out, int N) {
    int t = threadIdx.x;
    int w = t >> 6, lane = t & 63;
    float wl[C], mm[C];
#pragma unroll
    for (int j = 0; j < C; j += 4) {
        float4 a = *(const float4*)(linl_w + (size_t)lane * C + j);
        wl[j] = a.x; wl[j + 1] = a.y; wl[j + 2] = a.z; wl[j + 3] = a.w;
        float4 b = *(const float4*)(Mrow + (size_t)lane * C + j);
        mm[j] = b.x; mm[j + 1] = b.y; mm[j + 2] = b.z; mm[j + 3] = b.w;
    }
    float bl = linl_b[lane];
    float bcv = bc[lane];
    for (int n = blockIdx.x * 4 + w; n < N; n += gridDim.x * 4) {
        float xval = x[(size_t)n * C + lane];
        float aval = agg[(size_t)n * C + lane];
        int deg = cnt[n];
        float inv = 1.0f / (float)max(deg, 1);
        float ind = deg > 0 ? 1.f : 0.f;
        float acc1 = bl, acc2 = 0.f;
#pragma unroll
        for (int j = 0; j < C; ++j) {
            acc1 = fmaf(lanebc(xval, j), wl[j], acc1);
            acc2 = fmaf(lanebc(aval, j), mm[j], acc2);
        }
        out[(size_t)n * C + lane] = acc1 + inv * acc2 + ind * bcv;
    }
}

extern "C" void kernel_launch(void* const* d_in, const int* in_sizes, int n_in,
                              void* d_out, int out_size, void* d_ws, size_t ws_size,
                              hipStream_t stream) {
    const float* x      = (const float*)d_in[0];
    const int*   ei     = (const int*)d_in[1];
    const float* lin_w  = (const float*)d_in[2];
    const float* lin_b  = (const float*)d_in[3];
    const float* linl_w = (const float*)d_in[4];
    const float* linl_b = (const float*)d_in[5];
    const float* linr_w = (const float*)d_in[6];

    int N = in_sizes[0] / C;
    int E = in_sizes[1] / 2;

    // ws layout (4B units): cnt[N] | offs[N] | cursor[N] | bsums[256] | Mrow[4096] | bc[64] | ss[E]
    int* cnt    = (int*)d_ws;
    int* offs   = cnt + N;
    int* cursor = offs + N;
    int* bsums  = cursor + N;
    float* Mrow = (float*)(bsums + 256);
    float* bc   = Mrow + C * C;
    int* ss     = (int*)(bc + C);

    float* agg = (float*)d_out;  // raw neighbor sums accumulate in d_out

    hipMemsetAsync(cnt, 0, (size_t)N * sizeof(int), stream);

    precompute_wb<<<C, C, 0, stream>>>(lin_w, lin_b, linr_w, Mrow, bc);

    hist_kernel<<<2048, 256, 0, stream>>>(ei, cnt, E, N);

    int nb1 = (N + 1023) / 1024;
    scan1<<<nb1, 256, 0, stream>>>(cnt, offs, bsums, N);
    scan2<<<1, 256, 0, stream>>>(bsums, nb1);
    scan3<<<2048, 256, 0, stream>>>(offs, bsums, cursor, N);

    scatter_ids<<<2048, 256, 0, stream>>>(ei, cursor, ss, E, N);

    gather_kernel<<<2048, 256, 0, stream>>>(x, ss, offs, cnt, agg, N);

    matmul_kernel<<<2048, 256, 0, stream>>>(x, agg, cnt, linl_w, linl_b, Mrow, bc,
                                            (float*)d_out, N);
}

// Round 9
// 328.879 us; speedup vs baseline: 4.9288x; 1.1147x over previous
//
#include <hip/hip_runtime.h>

#define C 64
#define NPART 8

typedef __attribute__((ext_vector_type(8))) short bf16x8;
typedef __attribute__((ext_vector_type(4))) float f32x4;

// round-to-nearest-even f32 -> bf16 bits
__device__ __forceinline__ short f2bf(float f) {
    union { float f; unsigned u; } v; v.f = f;
    unsigned r = v.u + 0x7fff + ((v.u >> 16) & 1);
    return (short)(r >> 16);
}

__device__ __forceinline__ bf16x8 cvt8(const float* __restrict__ p, float scale) {
    bf16x8 r;
#pragma unroll
    for (int i = 0; i < 8; ++i) r[i] = f2bf(p[i] * scale);
    return r;
}

// Mrow[o*64+j] = sum_i linr_w[o][i] * lin_w[i][j]; bc[o] = linr_w[o]·lin_b
__global__ void precompute_wb(const float* __restrict__ lin_w,
                              const float* __restrict__ lin_b,
                              const float* __restrict__ linr_w,
                              float* __restrict__ Mrow,
                              float* __restrict__ bc) {
    int o = blockIdx.x;
    int j = threadIdx.x;
    float acc = 0.f;
#pragma unroll
    for (int i = 0; i < C; ++i)
        acc += linr_w[o * C + i] * lin_w[i * C + j];
    Mrow[o * C + j] = acc;
    if (j == 0) {
        float b = 0.f;
#pragma unroll
        for (int i = 0; i < C; ++i) b += linr_w[o * C + i] * lin_b[i];
        bc[o] = b;
    }
}

// degree histogram, XCD-partitioned by dst range (see scatter_ids comment)
__global__ __launch_bounds__(256) void hist_kernel(const int* __restrict__ ei,
                                                   int* cnt, int E, int N) {
    int part = blockIdx.x & (NPART - 1);
    int R = (N + NPART - 1) / NPART;
    int lo = part * R;
    int hi = min(N, lo + R);
    int bid = blockIdx.x >> 3;
    int nblk = gridDim.x >> 3;
    int i = bid * blockDim.x + threadIdx.x;
    int stride = nblk * blockDim.x;
    if ((E & 3) == 0) {
        const int4* d4 = (const int4*)(ei + E);
        int n4 = E >> 2;
        for (int k = i; k < n4; k += stride) {
            int4 v = d4[k];
            if (v.x >= lo && v.x < hi) atomicAdd(&cnt[v.x], 1);
            if (v.y >= lo && v.y < hi) atomicAdd(&cnt[v.y], 1);
            if (v.z >= lo && v.z < hi) atomicAdd(&cnt[v.z], 1);
            if (v.w >= lo && v.w < hi) atomicAdd(&cnt[v.w], 1);
        }
    } else {
        for (int e = i; e < E; e += stride) {
            int d = ei[E + e];
            if (d >= lo && d < hi) atomicAdd(&cnt[d], 1);
        }
    }
}

// scan pass 1: per-block (1024 elems) exclusive scan + block sums
__global__ __launch_bounds__(256) void scan1(const int* __restrict__ cnt,
                                             int* offs, int* bsums, int N) {
    __shared__ int tmp[256];
    int b = blockIdx.x, t = threadIdx.x;
    int base = b * 1024 + t * 4;
    int c0 = base + 0 < N ? cnt[base + 0] : 0;
    int c1 = base + 1 < N ? cnt[base + 1] : 0;
    int c2 = base + 2 < N ? cnt[base + 2] : 0;
    int c3 = base + 3 < N ? cnt[base + 3] : 0;
    int s = c0 + c1 + c2 + c3;
    tmp[t] = s;
    __syncthreads();
    for (int off = 1; off < 256; off <<= 1) {
        int u = (t >= off) ? tmp[t - off] : 0;
        __syncthreads();
        tmp[t] += u;
        __syncthreads();
    }
    int excl = tmp[t] - s;
    if (base + 0 < N) offs[base + 0] = excl; excl += c0;
    if (base + 1 < N) offs[base + 1] = excl; excl += c1;
    if (base + 2 < N) offs[base + 2] = excl; excl += c2;
    if (base + 3 < N) offs[base + 3] = excl;
    if (t == 255) bsums[b] = tmp[255];
}

// scan pass 2: exclusive scan of block sums (nb <= 256), single block
__global__ __launch_bounds__(256) void scan2(int* bsums, int nb) {
    __shared__ int tmp[256];
    int t = threadIdx.x;
    int v = t < nb ? bsums[t] : 0;
    tmp[t] = v;
    __syncthreads();
    for (int off = 1; off < 256; off <<= 1) {
        int u = (t >= off) ? tmp[t - off] : 0;
        __syncthreads();
        tmp[t] += u;
        __syncthreads();
    }
    if (t < nb) bsums[t] = tmp[t] - v;
}

// scan pass 3: add block offsets; init write cursors
__global__ __launch_bounds__(256) void scan3(int* offs, const int* __restrict__ bsums,
                                             int* cursor, int N) {
    int stride = gridDim.x * blockDim.x;
    for (int i = blockIdx.x * blockDim.x + threadIdx.x; i < N; i += stride) {
        int v = offs[i] + bsums[i >> 10];
        offs[i] = v;
        cursor[i] = v;
    }
}

// bucket-scatter src ids grouped by dst, XCD-partitioned by dst range:
// each partition's ss segment + cursor range is written by one XCD's blocks only,
// so partial 64B lines coalesce in that L2 (killed the 17x write amplification).
__global__ __launch_bounds__(256) void scatter_ids(const int* __restrict__ ei,
                                                   int* cursor, int* ss, int E, int N) {
    int part = blockIdx.x & (NPART - 1);
    int R = (N + NPART - 1) / NPART;
    int lo = part * R;
    int hi = min(N, lo + R);
    int bid = blockIdx.x >> 3;
    int nblk = gridDim.x >> 3;
    int i = bid * blockDim.x + threadIdx.x;
    int stride = nblk * blockDim.x;
    if ((E & 3) == 0) {
        const int4* s4 = (const int4*)ei;
        const int4* d4 = (const int4*)(ei + E);
        int n4 = E >> 2;
        for (int k = i; k < n4; k += stride) {
            int4 dv = d4[k];
            int4 sv = s4[k];
            if (dv.x >= lo && dv.x < hi) ss[atomicAdd(&cursor[dv.x], 1)] = sv.x;
            if (dv.y >= lo && dv.y < hi) ss[atomicAdd(&cursor[dv.y], 1)] = sv.y;
            if (dv.z >= lo && dv.z < hi) ss[atomicAdd(&cursor[dv.z], 1)] = sv.z;
            if (dv.w >= lo && dv.w < hi) ss[atomicAdd(&cursor[dv.w], 1)] = sv.w;
        }
    } else {
        for (int e = i; e < E; e += stride) {
            int d = ei[E + e];
            if (d >= lo && d < hi) ss[atomicAdd(&cursor[d], 1)] = ei[e];
        }
    }
}

// gather: agg[n][:] = sum over bucket of x[s][:]
// 4 groups of 16 lanes; each group loads one edge row as float4/lane; quad-unrolled MLP.
__global__ __launch_bounds__(256) void gather_kernel(const float* __restrict__ x,
                                                     const int* __restrict__ ss,
                                                     const int* __restrict__ offs,
                                                     const int* __restrict__ cnt,
                                                     float* __restrict__ agg, int N) {
    int t = threadIdx.x;
    int w = t >> 6, lane = t & 63;
    int lg = lane >> 4, li = lane & 15;
    for (int n = blockIdx.x * 4 + w; n < N; n += gridDim.x * 4) {
        int start = offs[n];
        int deg = cnt[n];
        float a0[4] = {0, 0, 0, 0}, a1[4] = {0, 0, 0, 0};
        float a2[4] = {0, 0, 0, 0}, a3[4] = {0, 0, 0, 0};
        for (int base = 0; base < deg; base += 64) {
            int cdeg = min(deg - base, 64);
            int sid = ss[start + base + min(lane, cdeg - 1)];
            int nsteps = (cdeg + 3) >> 2;
            int tt = 0;
            for (; tt + 4 <= nsteps; tt += 4) {
                int i0 = tt * 4 + lg;
                int i3 = i0 + 12;
                int s0 = __shfl(sid, i0);
                int s1 = __shfl(sid, i0 + 4);
                int s2 = __shfl(sid, i0 + 8);
                int s3 = __shfl(sid, min(i3, cdeg - 1));
                float w3 = (i3 < cdeg) ? 1.f : 0.f;
                float4 v0 = *(const float4*)(x + (size_t)s0 * C + (li << 2));
                float4 v1 = *(const float4*)(x + (size_t)s1 * C + (li << 2));
                float4 v2 = *(const float4*)(x + (size_t)s2 * C + (li << 2));
                float4 v3 = *(const float4*)(x + (size_t)s3 * C + (li << 2));
                a0[0] += v0.x; a0[1] += v0.y; a0[2] += v0.z; a0[3] += v0.w;
                a1[0] += v1.x; a1[1] += v1.y; a1[2] += v1.z; a1[3] += v1.w;
                a2[0] += v2.x; a2[1] += v2.y; a2[2] += v2.z; a2[3] += v2.w;
                a3[0] = fmaf(w3, v3.x, a3[0]); a3[1] = fmaf(w3, v3.y, a3[1]);
                a3[2] = fmaf(w3, v3.z, a3[2]); a3[3] = fmaf(w3, v3.w, a3[3]);
            }
            for (; tt + 2 <= nsteps; tt += 2) {
                int i0 = tt * 4 + lg;
                int i1 = i0 + 4;
                int s0 = __shfl(sid, i0);
                int s1 = __shfl(sid, min(i1, cdeg - 1));
                float w1 = (i1 < cdeg) ? 1.f : 0.f;
                float4 v0 = *(const float4*)(x + (size_t)s0 * C + (li << 2));
                float4 v1 = *(const float4*)(x + (size_t)s1 * C + (li << 2));
                a0[0] += v0.x; a0[1] += v0.y; a0[2] += v0.z; a0[3] += v0.w;
                a1[0] = fmaf(w1, v1.x, a1[0]); a1[1] = fmaf(w1, v1.y, a1[1]);
                a1[2] = fmaf(w1, v1.z, a1[2]); a1[3] = fmaf(w1, v1.w, a1[3]);
            }
            for (; tt < nsteps; ++tt) {
                int i0 = tt * 4 + lg;
                int s0 = __shfl(sid, min(i0, cdeg - 1));
                float w0 = (i0 < cdeg) ? 1.f : 0.f;
                float4 v0 = *(const float4*)(x + (size_t)s0 * C + (li << 2));
                a0[0] = fmaf(w0, v0.x, a0[0]); a0[1] = fmaf(w0, v0.y, a0[1]);
                a0[2] = fmaf(w0, v0.z, a0[2]); a0[3] = fmaf(w0, v0.w, a0[3]);
            }
        }
#pragma unroll
        for (int k = 0; k < 4; ++k) a0[k] += a1[k] + a2[k] + a3[k];
#pragma unroll
        for (int k = 0; k < 4; ++k) {
            a0[k] += __shfl_xor(a0[k], 16);
            a0[k] += __shfl_xor(a0[k], 32);
        }
        if (lane < 16) {
            float4 r;
            r.x = a0[0]; r.y = a0[1]; r.z = a0[2]; r.w = a0[3];
            *(float4*)(agg + (size_t)n * C + (li << 2)) = r;
        }
    }
}

// MFMA matmul: out[N][64] = bf16([x | agg*inv]) @ bf16(Wcat^T) + bl + ind*bc
// Wcat[o][0:64]=linl_w[o], Wcat[o][64:128]=Mrow[o]. One wave per 16-node tile.
// A frag (16x16x32 bf16): row=lane&15, k=(lane>>4)*8+i (8 contiguous k).
// B frag: col=lane&15, k=(lane>>4)*8+i.  C/D: col=lane&15, row=(lane>>4)*4+reg.
// agg aliases out: wave reads its 16 rows into fragments before storing them.
__global__ __launch_bounds__(256) void matmul_mfma(const float* __restrict__ x,
                                                   const float* agg,
                                                   const int* __restrict__ cnt,
                                                   const float* __restrict__ linl_w,
                                                   const float* __restrict__ linl_b,
                                                   const float* __restrict__ Mrow,
                                                   const float* __restrict__ bc,
                                                   float* out, int N) {
    int t = threadIdx.x;
    int wv = t >> 6, lane = t & 63;
    int lrow = lane & 15;
    int kblk = lane >> 4;   // 0..3
    int koff = kblk * 8;

    // B fragments loaded once: Bf[c][q]; col o = 16c+lrow; k = 32q+koff+i
    bf16x8 Bf[4][4];
#pragma unroll
    for (int c = 0; c < 4; ++c) {
        int o = c * 16 + lrow;
#pragma unroll
        for (int q = 0; q < 4; ++q) {
            const float* src = (q < 2) ? (linl_w + (size_t)o * C + q * 32 + koff)
                                       : (Mrow + (size_t)o * C + (q - 2) * 32 + koff);
            Bf[c][q] = cvt8(src, 1.0f);
        }
    }
    float blv[4], bcv[4];
#pragma unroll
    for (int c = 0; c < 4; ++c) {
        blv[c] = linl_b[c * 16 + lrow];
        bcv[c] = bc[c * 16 + lrow];
    }

    int ntiles = (N + 15) >> 4;
    int nw = gridDim.x * 4;
    for (int tile = blockIdx.x * 4 + wv; tile < ntiles; tile += nw) {
        int n0 = tile * 16;
        int ar = min(n0 + lrow, N - 1);
        float inva = 1.0f / (float)max(cnt[ar], 1);
        const float* xr = x + (size_t)ar * C;
        const float* gr = agg + (size_t)ar * C;
        bf16x8 Af[4];
        Af[0] = cvt8(xr + koff, 1.0f);
        Af[1] = cvt8(xr + 32 + koff, 1.0f);
        Af[2] = cvt8(gr + koff, inva);
        Af[3] = cvt8(gr + 32 + koff, inva);

        f32x4 acc[4] = {{0, 0, 0, 0}, {0, 0, 0, 0}, {0, 0, 0, 0}, {0, 0, 0, 0}};
#pragma unroll
        for (int q = 0; q < 4; ++q)
#pragma unroll
            for (int c = 0; c < 4; ++c)
                acc[c] = __builtin_amdgcn_mfma_f32_16x16x32_bf16(Af[q], Bf[c][q],
                                                                 acc[c], 0, 0, 0);

#pragma unroll
        for (int r = 0; r < 4; ++r) {
            int nrow = n0 + kblk * 4 + r;
            if (nrow < N) {
                float ind = cnt[nrow] > 0 ? 1.f : 0.f;
#pragma unroll
                for (int c = 0; c < 4; ++c)
                    out[(size_t)nrow * C + c * 16 + lrow] =
                        acc[c][r] + blv[c] + ind * bcv[c];
            }
        }
    }
}

extern "C" void kernel_launch(void* const* d_in, const int* in_sizes, int n_in,
                              void* d_out, int out_size, void* d_ws, size_t ws_size,
                              hipStream_t stream) {
    const float* x      = (const float*)d_in[0];
    const int*   ei     = (const int*)d_in[1];
    const float* lin_w  = (const float*)d_in[2];
    const float* lin_b  = (const float*)d_in[3];
    const float* linl_w = (const float*)d_in[4];
    const float* linl_b = (const float*)d_in[5];
    const float* linr_w = (const float*)d_in[6];

    int N = in_sizes[0] / C;
    int E = in_sizes[1] / 2;

    // ws layout (4B units): cnt[N] | offs[N] | cursor[N] | bsums[256] | Mrow[4096] | bc[64] | ss[E]
    int* cnt    = (int*)d_ws;
    int* offs   = cnt + N;
    int* cursor = offs + N;
    int* bsums  = cursor + N;
    float* Mrow = (float*)(bsums + 256);
    float* bc   = Mrow + C * C;
    int* ss     = (int*)(bc + C);

    float* agg = (float*)d_out;  // raw neighbor sums accumulate in d_out

    hipMemsetAsync(cnt, 0, (size_t)N * sizeof(int), stream);

    precompute_wb<<<C, C, 0, stream>>>(lin_w, lin_b, linr_w, Mrow, bc);

    hist_kernel<<<2048, 256, 0, stream>>>(ei, cnt, E, N);

    int nb1 = (N + 1023) / 1024;
    scan1<<<nb1, 256, 0, stream>>>(cnt, offs, bsums, N);
    scan2<<<1, 256, 0, stream>>>(bsums, nb1);
    scan3<<<2048, 256, 0, stream>>>(offs, bsums, cursor, N);

    scatter_ids<<<2048, 256, 0, stream>>>(ei, cursor, ss, E, N);

    gather_kernel<<<2048, 256, 0, stream>>>(x, ss, offs, cnt, agg, N);

    int ntiles = (N + 15) / 16;
    int mblocks = (ntiles + 3) / 4;
    if (mblocks > 2048) mblocks = 2048;
    matmul_mfma<<<mblocks, 256, 0, stream>>>(x, agg, cnt, linl_w, linl_b, Mrow, bc,
                                             (float*)d_out, N);
}